// Round 7
// baseline (5931.145 us; speedup 1.0000x reference)
//
#include <hip/hip_runtime.h>
#include <stdint.h>

// Problem constants
#define TT 256      // timesteps per phase
#define BB 256      // batch
#define II 128      // input dim
#define SS 256      // state dim
#define NTEAM 16    // row teams (16 batch rows each)
#define CGRP 16     // col-blocks per team
#define RB 16       // batch rows per role
#define CB 16       // state cols per role
#define NSTEP (2*TT)
#define NBLKG 64    // 64 blocks x 4 independent wave-roles = 256 roles

typedef _Float16 h16;
typedef _Float16 half8 __attribute__((ext_vector_type(8)));
typedef float f32x4 __attribute__((ext_vector_type(4)));
typedef unsigned int u32x4 __attribute__((ext_vector_type(4)));

// Exchange buffer: [parity][team][row 0..15][col_pair 0..127] of u64
//   u64 = { hi: step tag, lo: packed 2 x fp16 (even col in low half) }
// 2 * 16 * 16 * 128 * 8B = 512 KB in ws (memset of this size proven OK in r6).
// Tag-in-data => no flags, no drains, no barriers. Aligned 8B global accesses
// are single-copy atomic on AMDGPU, so a consumer either sees the old tag or
// the complete new {tag,data} word. Parity reuse is safe: a producer can only
// write step n+2 into a slot after gathering ALL of s_{n+1}, which requires
// every team member to have finished READING s_n from that slot.
#define XROW 128
#define XTEAM (RB * XROW)        // 2048 u64 per team
#define XPAR  (NTEAM * XTEAM)    // 32768 u64 per parity

__device__ __forceinline__ float sigmoidf_(float z) {
    return __builtin_amdgcn_rcpf(1.0f + __expf(-z));
}
__device__ __forceinline__ float tanhf_(float z) {
    return 1.0f - 2.0f * __builtin_amdgcn_rcpf(1.0f + __expf(2.0f * z));
}

__device__ __forceinline__ uint64_t ld_ag64(const uint64_t* p) {
    return __hip_atomic_load(p, __ATOMIC_RELAXED, __HIP_MEMORY_SCOPE_AGENT);
}
__device__ __forceinline__ void st_ag64(uint64_t* p, uint64_t v) {
    __hip_atomic_store(p, v, __ATOMIC_RELAXED, __HIP_MEMORY_SCOPE_AGENT);
}

struct Ptrs {
    const float *x;
    const float *Wi, *Ui, *Bi, *Wf, *Uf, *Bf, *Wo, *Uo, *Bo, *Wg, *Ug, *Bg;
    float* out;
    uint32_t* ws;
};

__global__ __launch_bounds__(256, 1) void lstm_wave(Ptrs p) {
    const int tid  = threadIdx.x;
    const int wid  = tid >> 6;             // wave id in block: 4 independent roles
    const int lane = tid & 63;
    const int role = blockIdx.x * 4 + wid; // 0..255
    const int team = role >> 4;            // batch rows [team*16, +16)
    const int cb   = role & 15;            // state cols [cb*16, +16)
    const int r0   = team * RB;
    const int c0   = cb * CB;
    const int lrow = lane & 15;            // A-row / C-col for this lane
    const int lgrp = lane >> 4;            // 0..3
    const int lk8  = lgrp * 8;             // k sub-offset within 32-chunk

    uint64_t* xch   = (uint64_t*)p.ws;
    uint64_t* slot0 = xch + (size_t)team * XTEAM;          // parity 0
    uint64_t* slot1 = xch + XPAR + (size_t)team * XTEAM;   // parity 1

    const float* Uptr[4] = {p.Ui, p.Uf, p.Uo, p.Ug};
    const float* Wptr[4] = {p.Wi, p.Wf, p.Wo, p.Wg};
    const float* Bptr[4] = {p.Bi, p.Bf, p.Bo, p.Bg};

    // ---- preload ALL 4 gates' B-fragments for this col-block ----
    // B layout (16x16x32): lane holds B[k=(lane>>4)*8+q][col=lane&15]
    half8 bU[4][8];
#pragma unroll
    for (int g = 0; g < 4; ++g) {
        const float* Ug = Uptr[g];
#pragma unroll
        for (int kc = 0; kc < 8; ++kc)
#pragma unroll
            for (int q = 0; q < 8; ++q)
                bU[g][kc][q] = (h16)Ug[(size_t)(kc * 32 + lk8 + q) * SS + c0 + lrow];
    }
    half8 bW[4][4];
#pragma unroll
    for (int g = 0; g < 4; ++g) {
        const float* Wg = Wptr[g];
#pragma unroll
        for (int kc = 0; kc < 4; ++kc)
#pragma unroll
            for (int q = 0; q < 8; ++q)
                bW[g][kc][q] = (h16)Wg[(size_t)(kc * 32 + lk8 + q) * SS + c0 + lrow];
    }
    float bias[4];
#pragma unroll
    for (int g = 0; g < 4; ++g) bias[g] = Bptr[g][c0 + lrow];

    // cell state: lane owns cells (row = lgrp*4+q, col = lrow), q=0..3
    float cst[4] = {0.f, 0.f, 0.f, 0.f};

    for (int n = 1; n <= NSTEP; ++n) {
        const bool enc = (n <= TT);

        // ---- issue this step's x-tile loads early (hide under gather RT) ----
        float4 xv[8];
        if (enc) {
            const float* xp = p.x + ((size_t)(n - 1) * BB + r0 + lrow) * II;
#pragma unroll
            for (int kc = 0; kc < 4; ++kc) {
                xv[2*kc]   = ((const float4*)(xp + kc * 32 + lk8))[0];
                xv[2*kc+1] = ((const float4*)(xp + kc * 32 + lk8))[1];
            }
        }

        f32x4 acc[4];
#pragma unroll
        for (int g = 0; g < 4; ++g) acc[g] = (f32x4){0.f, 0.f, 0.f, 0.f};

        // ---- gather s_{n-1} fragments from tagged exchange (retry stale) ----
        if (n >= 2) {
            const uint32_t want = (uint32_t)(n - 1);
            const uint64_t* gb = (((n - 1) & 1) ? slot1 : slot0) + (size_t)lrow * XROW;
            uint64_t gv[8][4];
#pragma unroll
            for (int kc = 0; kc < 8; ++kc)
#pragma unroll
                for (int j = 0; j < 4; ++j)
                    gv[kc][j] = ld_ag64(gb + kc * 16 + lgrp * 4 + j);   // 32 in flight
#pragma unroll
            for (int kc = 0; kc < 8; ++kc)
#pragma unroll
                for (int j = 0; j < 4; ++j) {
                    uint64_t v = gv[kc][j];
                    while (__builtin_expect((uint32_t)(v >> 32) != want, 0))
                        v = ld_ag64(gb + kc * 16 + lgrp * 4 + j);
                    gv[kc][j] = v;
                }
#pragma unroll
            for (int kc = 0; kc < 8; ++kc) {
                u32x4 t;
                t.x = (uint32_t)gv[kc][0]; t.y = (uint32_t)gv[kc][1];
                t.z = (uint32_t)gv[kc][2]; t.w = (uint32_t)gv[kc][3];
                half8 a = __builtin_bit_cast(half8, t);
#pragma unroll
                for (int g = 0; g < 4; ++g)
                    acc[g] = __builtin_amdgcn_mfma_f32_16x16x32_f16(a, bU[g][kc], acc[g], 0, 0, 0);
            }
        }

        // ---- x @ W contribution (encode only) ----
        if (enc) {
#pragma unroll
            for (int kc = 0; kc < 4; ++kc) {
                half8 xa;
                xa[0] = (h16)xv[2*kc].x;   xa[1] = (h16)xv[2*kc].y;
                xa[2] = (h16)xv[2*kc].z;   xa[3] = (h16)xv[2*kc].w;
                xa[4] = (h16)xv[2*kc+1].x; xa[5] = (h16)xv[2*kc+1].y;
                xa[6] = (h16)xv[2*kc+1].z; xa[7] = (h16)xv[2*kc+1].w;
#pragma unroll
                for (int g = 0; g < 4; ++g)
                    acc[g] = __builtin_amdgcn_mfma_f32_16x16x32_f16(xa, bW[g][kc], acc[g], 0, 0, 0);
            }
        }

        // ---- gates + state update, all in registers ----
        float sv[4];
#pragma unroll
        for (int q = 0; q < 4; ++q) {
            float zi = acc[0][q] + bias[0];
            float zf = acc[1][q] + bias[1];
            float zo = acc[2][q] + bias[2];
            float zg = acc[3][q] + bias[3];
            float ig = sigmoidf_(zi), fg = sigmoidf_(zf);
            float og = sigmoidf_(zo), gg = tanhf_(zg);
            cst[q] = cst[q] * fg + gg * ig;
            sv[q] = tanhf_(cst[q]) * og;
            if (!enc) {
                const int d = n - TT - 1;
                p.out[((size_t)d * BB + r0 + lgrp * 4 + q) * SS + c0 + lrow] = og;
            }
        }

        // ---- publish s_n as tagged u64 (fire-and-forget, no drain) ----
        if (n < NSTEP) {
            uint64_t* pb = ((n & 1) ? slot1 : slot0);
            const uint64_t tag = (uint64_t)(uint32_t)n << 32;
#pragma unroll
            for (int q = 0; q < 4; ++q) {
                float so = __shfl_xor(sv[q], 1);
                if ((lane & 1) == 0) {
                    uint16_t lo = __builtin_bit_cast(uint16_t, (h16)sv[q]);
                    uint16_t hi = __builtin_bit_cast(uint16_t, (h16)so);
                    uint64_t pk = tag | (uint64_t)((uint32_t)lo | ((uint32_t)hi << 16));
                    st_ag64(pb + (size_t)(lgrp * 4 + q) * XROW + cb * 8 + (lrow >> 1), pk);
                }
            }
        }
    }
}

extern "C" void kernel_launch(void* const* d_in, const int* in_sizes, int n_in,
                              void* d_out, int out_size, void* d_ws, size_t ws_size,
                              hipStream_t stream) {
    Ptrs p;
    p.x  = (const float*)d_in[0];
    p.Wi = (const float*)d_in[1];  p.Ui = (const float*)d_in[2];  p.Bi = (const float*)d_in[3];
    p.Wf = (const float*)d_in[4];  p.Uf = (const float*)d_in[5];  p.Bf = (const float*)d_in[6];
    p.Wo = (const float*)d_in[7];  p.Uo = (const float*)d_in[8];  p.Bo = (const float*)d_in[9];
    p.Wg = (const float*)d_in[10]; p.Ug = (const float*)d_in[11]; p.Bg = (const float*)d_in[12];
    p.out = (float*)d_out;
    p.ws  = (uint32_t*)d_ws;

    // zero tag words each launch -> no stale-tag acceptance, replay-safe
    hipMemsetAsync(d_ws, 0, (size_t)2 * XPAR * sizeof(uint64_t), stream);

    // Cooperative launch for guaranteed co-residency; if the runtime rejects
    // it (round-6 failure mode), fall back to a plain launch: 64 blocks on
    // 256 CUs are co-resident in practice, and the tag protocol needs no
    // grid-wide primitives.
    void* args[] = {&p};
    hipError_t e = hipLaunchCooperativeKernel(lstm_wave, dim3(NBLKG), dim3(256),
                                              args, 0, stream);
    if (e != hipSuccess) {
        hipLaunchKernelGGL(lstm_wave, dim3(NBLKG), dim3(256), 0, stream, p);
    }
}